// Round 5
// baseline (625.845 us; speedup 1.0000x reference)
//
#include <hip/hip_runtime.h>
#include <cstdint>
#include <cstddef>

// Problem constants (B=2, L=2048, D=1024, E=8, F=2048, TOP_K=2)
constexpr int T_TOK = 4096;      // B*L
constexpr int D_DIM = 1024;
constexpr int E_NUM = 8;
constexpr int F_DIM = 2048;
constexpr int C2F   = 4096;      // 2*F
constexpr int NPAIR = T_TOK * 2; // 8192 (token, slot) pairs

#define ALPHA_SW 1.702f
#define LIMIT_SW 9.0f

// ---------------- workspace layout (bytes) ----------------
constexpr size_t OFF_COUNTS  = 0;     // int[8]
constexpr size_t OFF_CURSOR  = 32;    // int[8]
constexpr size_t OFF_DONE    = 64;    // int
constexpr size_t OFF_OFFSETS = 96;    // int[9]
constexpr size_t OFF_SEL     = 192;
constexpr size_t OFF_WTS     = OFF_SEL    + (size_t)NPAIR * 4;
constexpr size_t OFF_PAIRTS  = OFF_WTS    + (size_t)NPAIR * 4;
constexpr size_t OFF_FACT    = 131328;                           // f_act bf16 [8192][2048]
constexpr size_t SZ_FACT     = (size_t)NPAIR * F_DIM * 2;        // 33.55 MB
constexpr size_t OFF_XG      = OFF_FACT + SZ_FACT;               // xg bf16 [8192][1024]
constexpr size_t SZ_XG       = (size_t)NPAIR * D_DIM * 2;        // 16.78 MB
constexpr size_t OFF_WB      = OFF_XG + SZ_XG;                   // w1b bf16 (67.1MB), then w2b (33.5MB)
// end = OFF_WB + 67.1MB = 117.5 MB — proven available (R2 fast path ran)

typedef __bf16 bf16x8 __attribute__((ext_vector_type(8)));
typedef float  f32x4  __attribute__((ext_vector_type(4)));

// round-half-up f32->bf16
__device__ __forceinline__ uint16_t bf16h(float f) {
  return (uint16_t)((__float_as_uint(f) + 0x8000u) >> 16);
}
__device__ __forceinline__ uint32_t pack2(float lo, float hi) {
  uint32_t ua = __float_as_uint(lo) + 0x8000u;
  uint32_t ub = __float_as_uint(hi) + 0x8000u;
  return __builtin_amdgcn_perm(ub, ua, 0x07060302); // {ub.hi16, ua.hi16}
}

// async global -> LDS, 16B/lane; dest = wave-uniform base + lane*16
__device__ __forceinline__ void gld_lds16(const uint16_t* g, uint16_t* l) {
  __builtin_amdgcn_global_load_lds(
      (const __attribute__((address_space(1))) unsigned int*)g,
      (__attribute__((address_space(3))) unsigned int*)l,
      16, 0, 0);
}

// fast swiglu: __expf + v_rcp (1-ulp ok for bf16 output; g→-inf limit handled: exp→inf, rcp→0)
__device__ __forceinline__ float swiglu_f(float g, float v) {
  g = fminf(g, LIMIT_SW);
  v = fminf(fmaxf(v, -LIMIT_SW), LIMIT_SW);
  float ex = __expf(-ALPHA_SW * g);
  return g * __builtin_amdgcn_rcpf(1.0f + ex) * (v + 1.0f);
}

// LDS tile: 128 rows x 64 bf16 (BK=64); row = 128B = 8 chunks of 16B.
// Swizzle: slot s of row r holds k-chunk s ^ (r&7). Conflict-free for
// ds_read_b128 within 8-lane phase groups (same mechanism that gave the
// measured 0 conflicts in R4's BK=32 variant).

// ---------------- K1: gate + top-2 + softmax + counts + offsets (fp64 routing) ----------------
__global__ __launch_bounds__(256) void gate_route_kernel(
    const float* __restrict__ x, const float* __restrict__ gate_w,
    int* __restrict__ sel, float* __restrict__ wts, int* __restrict__ counts,
    int* __restrict__ done, int* __restrict__ offsets) {
  int wave = threadIdx.x >> 6;
  int lane = threadIdx.x & 63;
  int t = blockIdx.x * 4 + wave;   // grid exactly covers T_TOK: no early return

  double acc[E_NUM];
#pragma unroll
  for (int e = 0; e < E_NUM; ++e) acc[e] = 0.0;

  const float* xr = x + (size_t)t * D_DIM;
#pragma unroll 4
  for (int i = 0; i < D_DIM / 64; ++i) {
    int d = i * 64 + lane;
    float xv = xr[d];
    const float* gw = gate_w + (size_t)d * E_NUM;
    float4 ga = *(const float4*)gw;
    float4 gb = *(const float4*)(gw + 4);
    acc[0] += (double)xv * (double)ga.x;
    acc[1] += (double)xv * (double)ga.y;
    acc[2] += (double)xv * (double)ga.z;
    acc[3] += (double)xv * (double)ga.w;
    acc[4] += (double)xv * (double)gb.x;
    acc[5] += (double)xv * (double)gb.y;
    acc[6] += (double)xv * (double)gb.z;
    acc[7] += (double)xv * (double)gb.w;
  }
#pragma unroll
  for (int off = 32; off >= 1; off >>= 1) {
#pragma unroll
    for (int e = 0; e < E_NUM; ++e) acc[e] += __shfl_down(acc[e], off, 64);
  }
  if (lane == 0) {
    int b0 = 0;
#pragma unroll
    for (int e = 1; e < E_NUM; ++e)
      if (acc[e] > acc[b0]) b0 = e;
    int b1 = (b0 == 0) ? 1 : 0;
#pragma unroll
    for (int e = 0; e < E_NUM; ++e)
      if (e != b0 && acc[e] > acc[b1] && e != b1) {
        if (e < b1 && acc[e] == acc[b1]) continue;
        if (acc[e] > acc[b1]) b1 = e;
      }
    double p0 = 1.0 / (1.0 + exp(acc[b1] - acc[b0]));
    sel[t * 2 + 0] = b0;
    sel[t * 2 + 1] = b1;
    wts[t * 2 + 0] = (float)p0;
    wts[t * 2 + 1] = (float)(1.0 - p0);
    atomicAdd(&counts[b0], 1);
    atomicAdd(&counts[b1], 1);
  }
  // last finished block computes the exclusive scan (saves a kernel launch)
  __syncthreads();
  if (threadIdx.x == 0) {
    __threadfence();
    int tk = atomicAdd(done, 1);
    if (tk == (int)gridDim.x - 1) {
      int s = 0;
      for (int e = 0; e < E_NUM; ++e) {
        int c = atomicAdd(&counts[e], 0);   // device-coherent read
        offsets[e] = s; s += c;
      }
      offsets[E_NUM] = s;
      __threadfence();
    }
  }
}

// ---------------- K2: scatter pair->slot + gather x row -> compacted bf16 ----------------
__global__ __launch_bounds__(256) void scatter_gather_kernel(
    const int* __restrict__ sel, const float* __restrict__ x,
    const int* __restrict__ offsets, int* __restrict__ cursor,
    int* __restrict__ pair_ts, uint16_t* __restrict__ xg) {
  __shared__ int s_idx;
  int p = blockIdx.x;
  if (threadIdx.x == 0) {
    int e = sel[p];
    int idx = offsets[e] + atomicAdd(&cursor[e], 1);
    pair_ts[idx] = p;
    s_idx = idx;
  }
  __syncthreads();
  int idx = s_idx;
  int t = p >> 1;
  int d = threadIdx.x * 4;
  float4 v = *(const float4*)&x[(size_t)t * D_DIM + d];
  uint2 o;
  o.x = pack2(v.x, v.y);
  o.y = pack2(v.z, v.w);
  *(uint2*)&xg[(size_t)idx * D_DIM + d] = o;
}

// ---------------- K3: w1 cvt + g/v row de-interleave ----------------
// Out row c_out: group q = c_out>>5, s = c_out&31. s<16 -> g of f=16q+s (c_in=32q+2s);
// s>=16 -> v of f=16q+s-16 (c_in=32q+2(s-16)+1). So lanes holding cols [32q..32q+15]
// have g, cols [32q+16..32q+31] have the matching v — same lane in the MFMA C layout.
__global__ __launch_bounds__(256) void cvt_w1_kernel(
    const float* __restrict__ w1, uint16_t* __restrict__ w1b) {
  int row = blockIdx.x;            // e*4096 + c_out
  int c_out = row & (C2F - 1);
  int e = row >> 12;
  int q = c_out >> 5, s = c_out & 31;
  int c_in = (q << 5) + ((s < 16) ? (s << 1) : (((s - 16) << 1) | 1));
  const float* src = w1 + ((size_t)e * C2F + c_in) * D_DIM + threadIdx.x * 4;
  float4 v = *(const float4*)src;
  uint2 o;
  o.x = pack2(v.x, v.y);
  o.y = pack2(v.z, v.w);
  *(uint2*)&w1b[(size_t)row * D_DIM + threadIdx.x * 4] = o;
}

// ---------------- K4: plain f32 -> bf16 convert (w2) ----------------
__global__ __launch_bounds__(256) void cvt_bf16_kernel(
    const float* __restrict__ src, uint16_t* __restrict__ dst, int n4) {
  int i = blockIdx.x * 256 + threadIdx.x;
  if (i >= n4) return;
  float4 v = ((const float4*)src)[i];
  uint2 o;
  o.x = pack2(v.x, v.y);
  o.y = pack2(v.z, v.w);
  ((uint2*)dst)[i] = o;
}

// ---------------- K5: GEMM1  f_act = swiglu(xg @ w1b^T + b1) ----------------
// 128x128 tile, BK=64, 4 waves (2x2), 4x4 accs/wave, all-async swizzled staging.
__global__ __launch_bounds__(256) void gemm1_kernel(
    const uint16_t* __restrict__ xg, const uint16_t* __restrict__ w1b,
    const float* __restrict__ b1, const int* __restrict__ offsets,
    uint16_t* __restrict__ f_act) {
  const int e = blockIdx.z;
  const int base = offsets[e];
  const int n_e = offsets[e + 1] - base;
  const int row0 = blockIdx.y * 128;
  if (row0 >= n_e) return;
  const int c0 = blockIdx.x * 128;

  __shared__ uint16_t As[128 * 64];   // 16 KB
  __shared__ uint16_t Bs[128 * 64];   // 16 KB

  const int tid = threadIdx.x;
  const int lane = tid & 63;
  const int wv = tid >> 6;
  const int wm = wv & 1, wn = wv >> 1;

  // staging: one gld_lds16 covers 8 rows (8 lanes/row of 128B); 4 per wave per operand
  const int srow = lane >> 3;                         // 0..7 within group
  const int schunk = ((lane & 7) ^ srow) * 8;         // source k-chunk (elems), swizzled
  const uint16_t* agp[4]; uint16_t* alds[4];
  const uint16_t* bgp[4]; uint16_t* blds[4];
#pragma unroll
  for (int j = 0; j < 4; ++j) {
    int tr = wv * 32 + 8 * j + srow;
    int ag = base + row0 + tr; if (ag > NPAIR - 1) ag = NPAIR - 1;
    agp[j] = xg + (size_t)ag * D_DIM + schunk;
    alds[j] = &As[(wv * 32 + 8 * j) * 64];
    bgp[j] = w1b + ((size_t)e * C2F + c0 + tr) * D_DIM + schunk;
    blds[j] = &Bs[(wv * 32 + 8 * j) * 64];
  }

  f32x4 acc[4][4];
#pragma unroll
  for (int mi = 0; mi < 4; ++mi)
#pragma unroll
    for (int ni = 0; ni < 4; ++ni) acc[mi][ni] = (f32x4){0.f, 0.f, 0.f, 0.f};

  // fragment readers: row = half*64 + mi*16 + (lane&15); k-chunk h*4+(lane>>4)
  // at slot = chunk ^ (row&7); row&7 = lane&7; slot(h=1) = slot(h=0) ^ 4
  const int r15 = lane & 15;
  const int s0 = (lane >> 4) ^ (lane & 7);
  const uint16_t* Ard0 = &As[(wm * 64 + r15) * 64 + s0 * 8];
  const uint16_t* Ard1 = &As[(wm * 64 + r15) * 64 + (s0 ^ 4) * 8];
  const uint16_t* Brd0 = &Bs[(wn * 64 + r15) * 64 + s0 * 8];
  const uint16_t* Brd1 = &Bs[(wn * 64 + r15) * 64 + (s0 ^ 4) * 8];

#pragma unroll
  for (int kt = 0; kt < D_DIM / 64; ++kt) {   // 16 iters, offsets fold to imms
    __syncthreads();
#pragma unroll
    for (int j = 0; j < 4; ++j) gld_lds16(agp[j] + kt * 64, alds[j]);
#pragma unroll
    for (int j = 0; j < 4; ++j) gld_lds16(bgp[j] + kt * 64, blds[j]);
    __syncthreads();

#pragma unroll
    for (int h = 0; h < 2; ++h) {
      const uint16_t* Ard = h ? Ard1 : Ard0;
      const uint16_t* Brd = h ? Brd1 : Brd0;
      bf16x8 af[4], bfv[4];
#pragma unroll
      for (int mi = 0; mi < 4; ++mi) af[mi] = *(const bf16x8*)(Ard + mi * 16 * 64);
#pragma unroll
      for (int ni = 0; ni < 4; ++ni) bfv[ni] = *(const bf16x8*)(Brd + ni * 16 * 64);
#pragma unroll
      for (int mi = 0; mi < 4; ++mi)
#pragma unroll
        for (int ni = 0; ni < 4; ++ni)
          acc[mi][ni] = __builtin_amdgcn_mfma_f32_16x16x32_bf16(af[mi], bfv[ni], acc[mi][ni], 0, 0, 0);
    }
  }

  // epilogue: g/v pairs live in the same lane (ni even=g, ni odd=v). 32 swiglu, no shfl.
  const float* b1e = b1 + (size_t)e * C2F;
  const int rq = (lane >> 4) * 4;
#pragma unroll
  for (int ji = 0; ji < 2; ++ji) {
    int gbase = c0 + wn * 64 + ji * 32;           // permuted-col group base (mult of 32)
    float bg = b1e[gbase + 2 * r15];              // un-permuted bias index for g
    float bv = b1e[gbase + 2 * r15 + 1];          // and for v
    int fcol = (gbase >> 1) + r15;                // f index = 16q + r15
#pragma unroll
    for (int mi = 0; mi < 4; ++mi)
#pragma unroll
      for (int r = 0; r < 4; ++r) {
        float g = acc[mi][2 * ji][r] + bg;
        float v = acc[mi][2 * ji + 1][r] + bv;
        float f = swiglu_f(g, v);
        int row_l = wm * 64 + mi * 16 + rq + r;
        if (row0 + row_l < n_e)
          f_act[(size_t)(base + row0 + row_l) * F_DIM + fcol] = bf16h(f);
      }
  }
}

// ---------------- K6: GEMM2 + fused weighted combine (atomicAdd into out) ----------------
__global__ __launch_bounds__(256) void gemm2_kernel(
    const uint16_t* __restrict__ f_act, const uint16_t* __restrict__ w2b,
    const float* __restrict__ b2, const int* __restrict__ offsets,
    const int* __restrict__ pair_ts, const float* __restrict__ wts,
    float* __restrict__ out) {
  const int e = blockIdx.z;
  const int base = offsets[e];
  const int n_e = offsets[e + 1] - base;
  const int row0 = blockIdx.y * 128;
  if (row0 >= n_e) return;
  const int c0 = blockIdx.x * 128;

  __shared__ uint16_t As[128 * 64];
  __shared__ uint16_t Bs[128 * 64];

  const int tid = threadIdx.x;
  const int lane = tid & 63;
  const int wv = tid >> 6;
  const int wm = wv & 1, wn = wv >> 1;

  const int srow = lane >> 3;
  const int schunk = ((lane & 7) ^ srow) * 8;
  const uint16_t* agp[4]; uint16_t* alds[4];
  const uint16_t* bgp[4]; uint16_t* blds[4];
#pragma unroll
  for (int j = 0; j < 4; ++j) {
    int tr = wv * 32 + 8 * j + srow;
    int ag = base + row0 + tr; if (ag > NPAIR - 1) ag = NPAIR - 1;
    agp[j] = f_act + (size_t)ag * F_DIM + schunk;
    alds[j] = &As[(wv * 32 + 8 * j) * 64];
    bgp[j] = w2b + ((size_t)e * D_DIM + c0 + tr) * F_DIM + schunk;
    blds[j] = &Bs[(wv * 32 + 8 * j) * 64];
  }

  f32x4 acc[4][4];
#pragma unroll
  for (int mi = 0; mi < 4; ++mi)
#pragma unroll
    for (int ni = 0; ni < 4; ++ni) acc[mi][ni] = (f32x4){0.f, 0.f, 0.f, 0.f};

  const int r15 = lane & 15;
  const int s0 = (lane >> 4) ^ (lane & 7);
  const uint16_t* Ard0 = &As[(wm * 64 + r15) * 64 + s0 * 8];
  const uint16_t* Ard1 = &As[(wm * 64 + r15) * 64 + (s0 ^ 4) * 8];
  const uint16_t* Brd0 = &Bs[(wn * 64 + r15) * 64 + s0 * 8];
  const uint16_t* Brd1 = &Bs[(wn * 64 + r15) * 64 + (s0 ^ 4) * 8];

#pragma unroll
  for (int kt = 0; kt < F_DIM / 64; ++kt) {   // 32 iters
    __syncthreads();
#pragma unroll
    for (int j = 0; j < 4; ++j) gld_lds16(agp[j] + kt * 64, alds[j]);
#pragma unroll
    for (int j = 0; j < 4; ++j) gld_lds16(bgp[j] + kt * 64, blds[j]);
    __syncthreads();

#pragma unroll
    for (int h = 0; h < 2; ++h) {
      const uint16_t* Ard = h ? Ard1 : Ard0;
      const uint16_t* Brd = h ? Brd1 : Brd0;
      bf16x8 af[4], bfv[4];
#pragma unroll
      for (int mi = 0; mi < 4; ++mi) af[mi] = *(const bf16x8*)(Ard + mi * 16 * 64);
#pragma unroll
      for (int ni = 0; ni < 4; ++ni) bfv[ni] = *(const bf16x8*)(Brd + ni * 16 * 64);
#pragma unroll
      for (int mi = 0; mi < 4; ++mi)
#pragma unroll
        for (int ni = 0; ni < 4; ++ni)
          acc[mi][ni] = __builtin_amdgcn_mfma_f32_16x16x32_bf16(af[mi], bfv[ni], acc[mi][ni], 0, 0, 0);
    }
  }

  // epilogue: bias + weighted atomic combine directly into out (no y buffer)
  float bias4[4]; int d4a[4];
#pragma unroll
  for (int ni = 0; ni < 4; ++ni) {
    d4a[ni] = c0 + wn * 64 + ni * 16 + r15;
    bias4[ni] = b2[(size_t)e * D_DIM + d4a[ni]];
  }
  const int rq = (lane >> 4) * 4;
#pragma unroll
  for (int mi = 0; mi < 4; ++mi)
#pragma unroll
    for (int r = 0; r < 4; ++r) {
      int grow = row0 + wm * 64 + mi * 16 + rq + r;
      if (grow >= n_e) continue;
      int pp = pair_ts[base + grow];
      float wt = wts[pp];
      size_t ob = (size_t)(pp >> 1) * D_DIM;
#pragma unroll
      for (int ni = 0; ni < 4; ++ni)
        atomicAdd(&out[ob + d4a[ni]], wt * (acc[mi][ni][r] + bias4[ni]));
    }
}

extern "C" void kernel_launch(void* const* d_in, const int* in_sizes, int n_in,
                              void* d_out, int out_size, void* d_ws, size_t ws_size,
                              hipStream_t stream) {
  const float* x      = (const float*)d_in[0];
  const float* gate_w = (const float*)d_in[1];
  const float* w1     = (const float*)d_in[2];
  const float* b1     = (const float*)d_in[3];
  const float* w2     = (const float*)d_in[4];
  const float* b2     = (const float*)d_in[5];
  float* out = (float*)d_out;

  char* ws = (char*)d_ws;
  int*      counts  = (int*)(ws + OFF_COUNTS);
  int*      cursor  = (int*)(ws + OFF_CURSOR);
  int*      done    = (int*)(ws + OFF_DONE);
  int*      offsets = (int*)(ws + OFF_OFFSETS);
  int*      sel     = (int*)(ws + OFF_SEL);
  float*    wts     = (float*)(ws + OFF_WTS);
  int*      pair_ts = (int*)(ws + OFF_PAIRTS);
  uint16_t* f_act   = (uint16_t*)(ws + OFF_FACT);
  uint16_t* xg      = (uint16_t*)(ws + OFF_XG);
  uint16_t* w1b     = (uint16_t*)(ws + OFF_WB);
  uint16_t* w2b     = (uint16_t*)(ws + OFF_WB);   // reuses w1b region after gemm1

  hipMemsetAsync(d_ws, 0, 132, stream);                                  // counts/cursor/done/offsets
  hipMemsetAsync(d_out, 0, (size_t)out_size * sizeof(float), stream);    // atomic-combine target
  cvt_w1_kernel<<<E_NUM * C2F, 256, 0, stream>>>(w1, w1b);
  gate_route_kernel<<<T_TOK / 4, 256, 0, stream>>>(x, gate_w, sel, wts, counts, done, offsets);
  scatter_gather_kernel<<<NPAIR, 256, 0, stream>>>(sel, x, offsets, cursor, pair_ts, xg);
  gemm1_kernel<<<dim3(C2F / 128, 64, E_NUM), 256, 0, stream>>>(xg, w1b, b1, offsets, f_act);
  cvt_bf16_kernel<<<(E_NUM * D_DIM * F_DIM / 4) / 256, 256, 0, stream>>>(
      w2, w2b, E_NUM * D_DIM * F_DIM / 4);
  gemm2_kernel<<<dim3(D_DIM / 128, 64, E_NUM), 256, 0, stream>>>(
      f_act, w2b, b2, offsets, pair_ts, wts, out);
}

// Round 6
// 600.801 us; speedup vs baseline: 1.0417x; 1.0417x over previous
//
#include <hip/hip_runtime.h>
#include <cstdint>
#include <cstddef>

// Problem constants (B=2, L=2048, D=1024, E=8, F=2048, TOP_K=2)
constexpr int T_TOK = 4096;      // B*L
constexpr int D_DIM = 1024;
constexpr int E_NUM = 8;
constexpr int F_DIM = 2048;
constexpr int C2F   = 4096;      // 2*F
constexpr int NPAIR = T_TOK * 2; // 8192 (token, slot) pairs

#define ALPHA_SW 1.702f
#define LIMIT_SW 9.0f

// ---------------- workspace layout (bytes) ----------------
constexpr size_t OFF_COUNTS  = 0;     // int[8]
constexpr size_t OFF_CURSOR  = 32;    // int[8]
constexpr size_t OFF_OFFSETS = 64;    // int[9]
constexpr size_t OFF_SEL     = 128;
constexpr size_t OFF_WTS     = OFF_SEL    + (size_t)NPAIR * 4;
constexpr size_t OFF_PAIRTS  = OFF_WTS    + (size_t)NPAIR * 4;
constexpr size_t OFF_POSOF   = OFF_PAIRTS + (size_t)NPAIR * 4;
constexpr size_t OFF_FACT    = 131328;                           // f_act bf16 [8192][2048]
constexpr size_t SZ_FACT     = (size_t)NPAIR * F_DIM * 2;        // 33.55 MB
constexpr size_t OFF_XG      = OFF_FACT + SZ_FACT;               // xg bf16 [8192][1024]
constexpr size_t SZ_XG       = (size_t)NPAIR * D_DIM * 2;        // 16.78 MB
constexpr size_t OFF_WB      = OFF_XG + SZ_XG;                   // w1b bf16 (67.1MB); later w2b(33.5)+y(33.5)
constexpr size_t SZ_W2B      = (size_t)E_NUM * D_DIM * F_DIM * 2;// 33.55 MB
constexpr size_t OFF_Y       = OFF_WB + SZ_W2B;                  // y fp32 [8192][1024], overlays w1b tail
// end = OFF_WB + 67.1 MB = 117.5 MB — proven available (R2/R4 fast path ran)

typedef __bf16 bf16x8 __attribute__((ext_vector_type(8)));
typedef float  f32x4  __attribute__((ext_vector_type(4)));

// round-half-up f32->bf16
__device__ __forceinline__ uint16_t bf16h(float f) {
  return (uint16_t)((__float_as_uint(f) + 0x8000u) >> 16);
}
__device__ __forceinline__ uint32_t pack2(float lo, float hi) {
  uint32_t ua = __float_as_uint(lo) + 0x8000u;
  uint32_t ub = __float_as_uint(hi) + 0x8000u;
  return __builtin_amdgcn_perm(ub, ua, 0x07060302); // {ub.hi16, ua.hi16}
}

// async global -> LDS, 16B/lane; dest = wave-uniform base + lane*16
__device__ __forceinline__ void gld_lds16(const uint16_t* g, uint16_t* l) {
  __builtin_amdgcn_global_load_lds(
      (const __attribute__((address_space(1))) unsigned int*)g,
      (__attribute__((address_space(3))) unsigned int*)l,
      16, 0, 0);
}

// fast swiglu (proven R5: absmax unchanged at 0.03125)
__device__ __forceinline__ float swiglu_f(float g, float v) {
  g = fminf(g, LIMIT_SW);
  v = fminf(fmaxf(v, -LIMIT_SW), LIMIT_SW);
  float ex = __expf(-ALPHA_SW * g);
  return g * __builtin_amdgcn_rcpf(1.0f + ex) * (v + 1.0f);
}

// ---------------- K1: gate + top-2 + softmax + counts ----------------
// One block per token: 256 threads x 4 d's each. Short chains, high TLP.
__global__ __launch_bounds__(256) void gate_route_kernel(
    const float* __restrict__ x, const float* __restrict__ gate_w,
    int* __restrict__ sel, float* __restrict__ wts, int* __restrict__ counts) {
  const int t = blockIdx.x;
  const int tid = threadIdx.x;
  const int lane = tid & 63, wv = tid >> 6;

  __shared__ double red[4][E_NUM];

  float4 xv = *(const float4*)&x[(size_t)t * D_DIM + tid * 4];
  const float* gw = gate_w + (size_t)tid * 4 * E_NUM;
  float4 g0a = *(const float4*)(gw + 0),  g0b = *(const float4*)(gw + 4);
  float4 g1a = *(const float4*)(gw + 8),  g1b = *(const float4*)(gw + 12);
  float4 g2a = *(const float4*)(gw + 16), g2b = *(const float4*)(gw + 20);
  float4 g3a = *(const float4*)(gw + 24), g3b = *(const float4*)(gw + 28);

  double acc[E_NUM];
  double x0 = xv.x, x1 = xv.y, x2 = xv.z, x3 = xv.w;
  acc[0] = x0*(double)g0a.x + x1*(double)g1a.x + x2*(double)g2a.x + x3*(double)g3a.x;
  acc[1] = x0*(double)g0a.y + x1*(double)g1a.y + x2*(double)g2a.y + x3*(double)g3a.y;
  acc[2] = x0*(double)g0a.z + x1*(double)g1a.z + x2*(double)g2a.z + x3*(double)g3a.z;
  acc[3] = x0*(double)g0a.w + x1*(double)g1a.w + x2*(double)g2a.w + x3*(double)g3a.w;
  acc[4] = x0*(double)g0b.x + x1*(double)g1b.x + x2*(double)g2b.x + x3*(double)g3b.x;
  acc[5] = x0*(double)g0b.y + x1*(double)g1b.y + x2*(double)g2b.y + x3*(double)g3b.y;
  acc[6] = x0*(double)g0b.z + x1*(double)g1b.z + x2*(double)g2b.z + x3*(double)g3b.z;
  acc[7] = x0*(double)g0b.w + x1*(double)g1b.w + x2*(double)g2b.w + x3*(double)g3b.w;

#pragma unroll
  for (int off = 32; off >= 1; off >>= 1) {
#pragma unroll
    for (int e = 0; e < E_NUM; ++e) acc[e] += __shfl_down(acc[e], off, 64);
  }
  if (lane == 0) {
#pragma unroll
    for (int e = 0; e < E_NUM; ++e) red[wv][e] = acc[e];
  }
  __syncthreads();
  if (tid == 0) {
#pragma unroll
    for (int e = 0; e < E_NUM; ++e)
      acc[e] = red[0][e] + red[1][e] + red[2][e] + red[3][e];
    int b0 = 0;
#pragma unroll
    for (int e = 1; e < E_NUM; ++e)
      if (acc[e] > acc[b0]) b0 = e;
    int b1 = (b0 == 0) ? 1 : 0;
#pragma unroll
    for (int e = 0; e < E_NUM; ++e)
      if (e != b0 && acc[e] > acc[b1] && e != b1) {
        if (e < b1 && acc[e] == acc[b1]) continue;
        if (acc[e] > acc[b1]) b1 = e;
      }
    double p0 = 1.0 / (1.0 + exp(acc[b1] - acc[b0]));
    sel[t * 2 + 0] = b0;
    sel[t * 2 + 1] = b1;
    wts[t * 2 + 0] = (float)p0;
    wts[t * 2 + 1] = (float)(1.0 - p0);
    atomicAdd(&counts[b0], 1);
    atomicAdd(&counts[b1], 1);
  }
}

// ---------------- K2: exclusive prefix scan over 8 counts ----------------
__global__ void scan_kernel(const int* __restrict__ counts, int* __restrict__ offsets) {
  if (threadIdx.x == 0 && blockIdx.x == 0) {
    int s = 0;
    for (int e = 0; e < E_NUM; ++e) { offsets[e] = s; s += counts[e]; }
    offsets[E_NUM] = s;
  }
}

// ---------------- K3: scatter pair->slot + gather x row -> compacted bf16 ----------------
__global__ __launch_bounds__(256) void scatter_gather_kernel(
    const int* __restrict__ sel, const float* __restrict__ x,
    const int* __restrict__ offsets, int* __restrict__ cursor,
    int* __restrict__ pair_ts, int* __restrict__ pos_of, uint16_t* __restrict__ xg) {
  __shared__ int s_idx;
  int p = blockIdx.x;
  if (threadIdx.x == 0) {
    int e = sel[p];
    int idx = offsets[e] + atomicAdd(&cursor[e], 1);
    pair_ts[idx] = p;
    pos_of[p] = idx;
    s_idx = idx;
  }
  __syncthreads();
  int idx = s_idx;
  int t = p >> 1;
  int d = threadIdx.x * 4;
  float4 v = *(const float4*)&x[(size_t)t * D_DIM + d];
  uint2 o;
  o.x = pack2(v.x, v.y);
  o.y = pack2(v.z, v.w);
  *(uint2*)&xg[(size_t)idx * D_DIM + d] = o;
}

// ---------------- K4: w1 cvt + g/v row de-interleave (proven R5) ----------------
__global__ __launch_bounds__(256) void cvt_w1_kernel(
    const float* __restrict__ w1, uint16_t* __restrict__ w1b) {
  int row = blockIdx.x;            // e*4096 + c_out
  int c_out = row & (C2F - 1);
  int e = row >> 12;
  int q = c_out >> 5, s = c_out & 31;
  int c_in = (q << 5) + ((s < 16) ? (s << 1) : (((s - 16) << 1) | 1));
  const float* src = w1 + ((size_t)e * C2F + c_in) * D_DIM + threadIdx.x * 4;
  float4 v = *(const float4*)src;
  uint2 o;
  o.x = pack2(v.x, v.y);
  o.y = pack2(v.z, v.w);
  *(uint2*)&w1b[(size_t)row * D_DIM + threadIdx.x * 4] = o;
}

// ---------------- K5: plain f32 -> bf16 convert (w2) ----------------
__global__ __launch_bounds__(256) void cvt_bf16_kernel(
    const float* __restrict__ src, uint16_t* __restrict__ dst, int n4) {
  int i = blockIdx.x * 256 + threadIdx.x;
  if (i >= n4) return;
  float4 v = ((const float4*)src)[i];
  uint2 o;
  o.x = pack2(v.x, v.y);
  o.y = pack2(v.z, v.w);
  ((uint2*)dst)[i] = o;
}

// LDS tile: 128 rows x 64 bf16 (BK=64); row = 128B = 8 chunks of 16B.
// Swizzle: slot s of row r holds k-chunk s ^ (r&7) — conflict-free (R5-verified).

// ---------------- K6: GEMM1  f_act = swiglu(xg @ w1b^T + b1) ----------------
__global__ __launch_bounds__(256) void gemm1_kernel(
    const uint16_t* __restrict__ xg, const uint16_t* __restrict__ w1b,
    const float* __restrict__ b1, const int* __restrict__ offsets,
    uint16_t* __restrict__ f_act) {
  const int e = blockIdx.z;
  const int base = offsets[e];
  const int n_e = offsets[e + 1] - base;
  const int row0 = blockIdx.y * 128;
  if (row0 >= n_e) return;
  const int c0 = blockIdx.x * 128;

  __shared__ uint16_t As[128 * 64];   // 16 KB
  __shared__ uint16_t Bs[128 * 64];   // 16 KB

  const int tid = threadIdx.x;
  const int lane = tid & 63;
  const int wv = tid >> 6;
  const int wm = wv & 1, wn = wv >> 1;

  const int srow = lane >> 3;
  const int schunk = ((lane & 7) ^ srow) * 8;
  const uint16_t* agp[4]; uint16_t* alds[4];
  const uint16_t* bgp[4]; uint16_t* blds[4];
#pragma unroll
  for (int j = 0; j < 4; ++j) {
    int tr = wv * 32 + 8 * j + srow;
    int ag = base + row0 + tr; if (ag > NPAIR - 1) ag = NPAIR - 1;
    agp[j] = xg + (size_t)ag * D_DIM + schunk;
    alds[j] = &As[(wv * 32 + 8 * j) * 64];
    bgp[j] = w1b + ((size_t)e * C2F + c0 + tr) * D_DIM + schunk;
    blds[j] = &Bs[(wv * 32 + 8 * j) * 64];
  }

  f32x4 acc[4][4];
#pragma unroll
  for (int mi = 0; mi < 4; ++mi)
#pragma unroll
    for (int ni = 0; ni < 4; ++ni) acc[mi][ni] = (f32x4){0.f, 0.f, 0.f, 0.f};

  const int r15 = lane & 15;
  const int s0 = (lane >> 4) ^ (lane & 7);
  const uint16_t* Ard0 = &As[(wm * 64 + r15) * 64 + s0 * 8];
  const uint16_t* Ard1 = &As[(wm * 64 + r15) * 64 + (s0 ^ 4) * 8];
  const uint16_t* Brd0 = &Bs[(wn * 64 + r15) * 64 + s0 * 8];
  const uint16_t* Brd1 = &Bs[(wn * 64 + r15) * 64 + (s0 ^ 4) * 8];

#pragma unroll
  for (int kt = 0; kt < D_DIM / 64; ++kt) {
    __syncthreads();
#pragma unroll
    for (int j = 0; j < 4; ++j) gld_lds16(agp[j] + kt * 64, alds[j]);
#pragma unroll
    for (int j = 0; j < 4; ++j) gld_lds16(bgp[j] + kt * 64, blds[j]);
    __syncthreads();

#pragma unroll
    for (int h = 0; h < 2; ++h) {
      const uint16_t* Ard = h ? Ard1 : Ard0;
      const uint16_t* Brd = h ? Brd1 : Brd0;
      bf16x8 af[4], bfv[4];
#pragma unroll
      for (int mi = 0; mi < 4; ++mi) af[mi] = *(const bf16x8*)(Ard + mi * 16 * 64);
#pragma unroll
      for (int ni = 0; ni < 4; ++ni) bfv[ni] = *(const bf16x8*)(Brd + ni * 16 * 64);
#pragma unroll
      for (int mi = 0; mi < 4; ++mi)
#pragma unroll
        for (int ni = 0; ni < 4; ++ni)
          acc[mi][ni] = __builtin_amdgcn_mfma_f32_16x16x32_bf16(af[mi], bfv[ni], acc[mi][ni], 0, 0, 0);
    }
  }

  // epilogue: g/v in same lane (ni even=g, ni odd=v); 32 swiglu, no shfl (proven R5)
  const float* b1e = b1 + (size_t)e * C2F;
  const int rq = (lane >> 4) * 4;
#pragma unroll
  for (int ji = 0; ji < 2; ++ji) {
    int gbase = c0 + wn * 64 + ji * 32;
    float bg = b1e[gbase + 2 * r15];
    float bv = b1e[gbase + 2 * r15 + 1];
    int fcol = (gbase >> 1) + r15;
#pragma unroll
    for (int mi = 0; mi < 4; ++mi)
#pragma unroll
      for (int r = 0; r < 4; ++r) {
        float g = acc[mi][2 * ji][r] + bg;
        float v = acc[mi][2 * ji + 1][r] + bv;
        float f = swiglu_f(g, v);
        int row_l = wm * 64 + mi * 16 + rq + r;
        if (row0 + row_l < n_e)
          f_act[(size_t)(base + row0 + row_l) * F_DIM + fcol] = bf16h(f);
      }
  }
}

// ---------------- K7: GEMM2  y = f_act @ w2b^T + b2  (plain stores) ----------------
__global__ __launch_bounds__(256) void gemm2_kernel(
    const uint16_t* __restrict__ f_act, const uint16_t* __restrict__ w2b,
    const float* __restrict__ b2, const int* __restrict__ offsets,
    float* __restrict__ y) {
  const int e = blockIdx.z;
  const int base = offsets[e];
  const int n_e = offsets[e + 1] - base;
  const int row0 = blockIdx.y * 128;
  if (row0 >= n_e) return;
  const int c0 = blockIdx.x * 128;

  __shared__ uint16_t As[128 * 64];
  __shared__ uint16_t Bs[128 * 64];

  const int tid = threadIdx.x;
  const int lane = tid & 63;
  const int wv = tid >> 6;
  const int wm = wv & 1, wn = wv >> 1;

  const int srow = lane >> 3;
  const int schunk = ((lane & 7) ^ srow) * 8;
  const uint16_t* agp[4]; uint16_t* alds[4];
  const uint16_t* bgp[4]; uint16_t* blds[4];
#pragma unroll
  for (int j = 0; j < 4; ++j) {
    int tr = wv * 32 + 8 * j + srow;
    int ag = base + row0 + tr; if (ag > NPAIR - 1) ag = NPAIR - 1;
    agp[j] = f_act + (size_t)ag * F_DIM + schunk;
    alds[j] = &As[(wv * 32 + 8 * j) * 64];
    bgp[j] = w2b + ((size_t)e * D_DIM + c0 + tr) * F_DIM + schunk;
    blds[j] = &Bs[(wv * 32 + 8 * j) * 64];
  }

  f32x4 acc[4][4];
#pragma unroll
  for (int mi = 0; mi < 4; ++mi)
#pragma unroll
    for (int ni = 0; ni < 4; ++ni) acc[mi][ni] = (f32x4){0.f, 0.f, 0.f, 0.f};

  const int r15 = lane & 15;
  const int s0 = (lane >> 4) ^ (lane & 7);
  const uint16_t* Ard0 = &As[(wm * 64 + r15) * 64 + s0 * 8];
  const uint16_t* Ard1 = &As[(wm * 64 + r15) * 64 + (s0 ^ 4) * 8];
  const uint16_t* Brd0 = &Bs[(wn * 64 + r15) * 64 + s0 * 8];
  const uint16_t* Brd1 = &Bs[(wn * 64 + r15) * 64 + (s0 ^ 4) * 8];

#pragma unroll
  for (int kt = 0; kt < F_DIM / 64; ++kt) {
    __syncthreads();
#pragma unroll
    for (int j = 0; j < 4; ++j) gld_lds16(agp[j] + kt * 64, alds[j]);
#pragma unroll
    for (int j = 0; j < 4; ++j) gld_lds16(bgp[j] + kt * 64, blds[j]);
    __syncthreads();

#pragma unroll
    for (int h = 0; h < 2; ++h) {
      const uint16_t* Ard = h ? Ard1 : Ard0;
      const uint16_t* Brd = h ? Brd1 : Brd0;
      bf16x8 af[4], bfv[4];
#pragma unroll
      for (int mi = 0; mi < 4; ++mi) af[mi] = *(const bf16x8*)(Ard + mi * 16 * 64);
#pragma unroll
      for (int ni = 0; ni < 4; ++ni) bfv[ni] = *(const bf16x8*)(Brd + ni * 16 * 64);
#pragma unroll
      for (int mi = 0; mi < 4; ++mi)
#pragma unroll
        for (int ni = 0; ni < 4; ++ni)
          acc[mi][ni] = __builtin_amdgcn_mfma_f32_16x16x32_bf16(af[mi], bfv[ni], acc[mi][ni], 0, 0, 0);
    }
  }

  // epilogue: bias + plain stores into compacted y (no atomics; R4-measured-better)
  float bias4[4]; int d4a[4];
#pragma unroll
  for (int ni = 0; ni < 4; ++ni) {
    d4a[ni] = c0 + wn * 64 + ni * 16 + r15;
    bias4[ni] = b2[(size_t)e * D_DIM + d4a[ni]];
  }
  const int rq = (lane >> 4) * 4;
#pragma unroll
  for (int mi = 0; mi < 4; ++mi)
#pragma unroll
    for (int r = 0; r < 4; ++r) {
      int grow = row0 + wm * 64 + mi * 16 + rq + r;
      if (grow >= n_e) continue;
      size_t yb = (size_t)(base + grow) * D_DIM;
#pragma unroll
      for (int ni = 0; ni < 4; ++ni)
        y[yb + d4a[ni]] = acc[mi][ni][r] + bias4[ni];
    }
}

// ---------------- K8: combine the two expert outputs per token ----------------
__global__ __launch_bounds__(256) void combine_kernel(
    const float* __restrict__ y, const int* __restrict__ pos_of,
    const float* __restrict__ wts, float* __restrict__ out) {
  int t = blockIdx.x;
  int d4 = threadIdx.x * 4;
  int p0 = pos_of[t * 2], p1 = pos_of[t * 2 + 1];
  float w0 = wts[t * 2], w1v = wts[t * 2 + 1];
  float4 a = *(const float4*)&y[(size_t)p0 * D_DIM + d4];
  float4 b = *(const float4*)&y[(size_t)p1 * D_DIM + d4];
  float4 o;
  o.x = w0 * a.x + w1v * b.x;
  o.y = w0 * a.y + w1v * b.y;
  o.z = w0 * a.z + w1v * b.z;
  o.w = w0 * a.w + w1v * b.w;
  *(float4*)&out[(size_t)t * D_DIM + d4] = o;
}

extern "C" void kernel_launch(void* const* d_in, const int* in_sizes, int n_in,
                              void* d_out, int out_size, void* d_ws, size_t ws_size,
                              hipStream_t stream) {
  const float* x      = (const float*)d_in[0];
  const float* gate_w = (const float*)d_in[1];
  const float* w1     = (const float*)d_in[2];
  const float* b1     = (const float*)d_in[3];
  const float* w2     = (const float*)d_in[4];
  const float* b2     = (const float*)d_in[5];
  float* out = (float*)d_out;

  char* ws = (char*)d_ws;
  int*      counts  = (int*)(ws + OFF_COUNTS);
  int*      cursor  = (int*)(ws + OFF_CURSOR);
  int*      offsets = (int*)(ws + OFF_OFFSETS);
  int*      sel     = (int*)(ws + OFF_SEL);
  float*    wts     = (float*)(ws + OFF_WTS);
  int*      pair_ts = (int*)(ws + OFF_PAIRTS);
  int*      pos_of  = (int*)(ws + OFF_POSOF);
  uint16_t* f_act   = (uint16_t*)(ws + OFF_FACT);
  uint16_t* xg      = (uint16_t*)(ws + OFF_XG);
  uint16_t* w1b     = (uint16_t*)(ws + OFF_WB);
  uint16_t* w2b     = (uint16_t*)(ws + OFF_WB);   // reuses w1b region after gemm1
  float*    yb      = (float*)(ws + OFF_Y);       // overlays w1b tail

  hipMemsetAsync(d_ws, 0, 64, stream);  // counts + cursor
  cvt_w1_kernel<<<E_NUM * C2F, 256, 0, stream>>>(w1, w1b);
  gate_route_kernel<<<T_TOK, 256, 0, stream>>>(x, gate_w, sel, wts, counts);
  scan_kernel<<<1, 64, 0, stream>>>(counts, offsets);
  scatter_gather_kernel<<<NPAIR, 256, 0, stream>>>(sel, x, offsets, cursor, pair_ts, pos_of, xg);
  gemm1_kernel<<<dim3(C2F / 128, 64, E_NUM), 256, 0, stream>>>(xg, w1b, b1, offsets, f_act);
  cvt_bf16_kernel<<<(E_NUM * D_DIM * F_DIM / 4) / 256, 256, 0, stream>>>(
      w2, w2b, E_NUM * D_DIM * F_DIM / 4);
  gemm2_kernel<<<dim3(D_DIM / 128, 64, E_NUM), 256, 0, stream>>>(f_act, w2b, b2, offsets, yb);
  combine_kernel<<<T_TOK, 256, 0, stream>>>(yb, pos_of, wts, out);
}

// Round 7
// 434.007 us; speedup vs baseline: 1.4420x; 1.3843x over previous
//
#include <hip/hip_runtime.h>
#include <cstdint>
#include <cstddef>

// Problem constants (B=2, L=2048, D=1024, E=8, F=2048, TOP_K=2)
constexpr int T_TOK = 4096;      // B*L
constexpr int D_DIM = 1024;
constexpr int E_NUM = 8;
constexpr int F_DIM = 2048;
constexpr int C2F   = 4096;      // 2*F
constexpr int NPAIR = T_TOK * 2; // 8192 (token, slot) pairs

#define ALPHA_SW 1.702f
#define LIMIT_SW 9.0f

// ---------------- workspace layout (bytes) ----------------
constexpr size_t OFF_OFFSETS = 0;     // int[9]
constexpr size_t OFF_SEL     = 128;
constexpr size_t OFF_WTS     = OFF_SEL    + (size_t)NPAIR * 4;
constexpr size_t OFF_POSOF   = OFF_WTS    + (size_t)NPAIR * 4;
constexpr size_t OFF_FACT    = 131328;                           // f_act bf16 [8192][2048]
constexpr size_t SZ_FACT     = (size_t)NPAIR * F_DIM * 2;        // 33.55 MB
constexpr size_t OFF_XG      = OFF_FACT + SZ_FACT;               // xg bf16 [8192][1024]
constexpr size_t SZ_XG       = (size_t)NPAIR * D_DIM * 2;        // 16.78 MB
constexpr size_t OFF_WB      = OFF_XG + SZ_XG;                   // w1b bf16 (67.1MB); later w2b(33.5)+y(33.5)
constexpr size_t SZ_W2B      = (size_t)E_NUM * D_DIM * F_DIM * 2;// 33.55 MB
constexpr size_t OFF_Y       = OFF_WB + SZ_W2B;                  // y fp32 [8192][1024], overlays w1b tail
// end = OFF_WB + 67.1 MB = 117.5 MB — proven available (R2/R4/R6 ran this footprint)

typedef __bf16 bf16x8 __attribute__((ext_vector_type(8)));
typedef float  f32x4  __attribute__((ext_vector_type(4)));

// round-half-up f32->bf16
__device__ __forceinline__ uint16_t bf16h(float f) {
  return (uint16_t)((__float_as_uint(f) + 0x8000u) >> 16);
}
__device__ __forceinline__ uint32_t pack2(float lo, float hi) {
  uint32_t ua = __float_as_uint(lo) + 0x8000u;
  uint32_t ub = __float_as_uint(hi) + 0x8000u;
  return __builtin_amdgcn_perm(ub, ua, 0x07060302); // {ub.hi16, ua.hi16}
}

// async global -> LDS, 16B/lane; dest = wave-uniform base + lane*16
__device__ __forceinline__ void gld_lds16(const uint16_t* g, uint16_t* l) {
  __builtin_amdgcn_global_load_lds(
      (const __attribute__((address_space(1))) unsigned int*)g,
      (__attribute__((address_space(3))) unsigned int*)l,
      16, 0, 0);
}

// fast swiglu (proven R5/R6: absmax unchanged at 0.03125)
__device__ __forceinline__ float swiglu_f(float g, float v) {
  g = fminf(g, LIMIT_SW);
  v = fminf(fmaxf(v, -LIMIT_SW), LIMIT_SW);
  float ex = __expf(-ALPHA_SW * g);
  return g * __builtin_amdgcn_rcpf(1.0f + ex) * (v + 1.0f);
}

// ---------------- K1: gate + top-2 + softmax (NO atomics) ----------------
__global__ __launch_bounds__(256) void gate_route_kernel(
    const float* __restrict__ x, const float* __restrict__ gate_w,
    int* __restrict__ sel, float* __restrict__ wts) {
  const int t = blockIdx.x;
  const int tid = threadIdx.x;
  const int lane = tid & 63, wv = tid >> 6;

  __shared__ double red[4][E_NUM];

  float4 xv = *(const float4*)&x[(size_t)t * D_DIM + tid * 4];
  const float* gw = gate_w + (size_t)tid * 4 * E_NUM;
  float4 g0a = *(const float4*)(gw + 0),  g0b = *(const float4*)(gw + 4);
  float4 g1a = *(const float4*)(gw + 8),  g1b = *(const float4*)(gw + 12);
  float4 g2a = *(const float4*)(gw + 16), g2b = *(const float4*)(gw + 20);
  float4 g3a = *(const float4*)(gw + 24), g3b = *(const float4*)(gw + 28);

  double acc[E_NUM];
  double x0 = xv.x, x1 = xv.y, x2 = xv.z, x3 = xv.w;
  acc[0] = x0*(double)g0a.x + x1*(double)g1a.x + x2*(double)g2a.x + x3*(double)g3a.x;
  acc[1] = x0*(double)g0a.y + x1*(double)g1a.y + x2*(double)g2a.y + x3*(double)g3a.y;
  acc[2] = x0*(double)g0a.z + x1*(double)g1a.z + x2*(double)g2a.z + x3*(double)g3a.z;
  acc[3] = x0*(double)g0a.w + x1*(double)g1a.w + x2*(double)g2a.w + x3*(double)g3a.w;
  acc[4] = x0*(double)g0b.x + x1*(double)g1b.x + x2*(double)g2b.x + x3*(double)g3b.x;
  acc[5] = x0*(double)g0b.y + x1*(double)g1b.y + x2*(double)g2b.y + x3*(double)g3b.y;
  acc[6] = x0*(double)g0b.z + x1*(double)g1b.z + x2*(double)g2b.z + x3*(double)g3b.z;
  acc[7] = x0*(double)g0b.w + x1*(double)g1b.w + x2*(double)g2b.w + x3*(double)g3b.w;

#pragma unroll
  for (int off = 32; off >= 1; off >>= 1) {
#pragma unroll
    for (int e = 0; e < E_NUM; ++e) acc[e] += __shfl_down(acc[e], off, 64);
  }
  if (lane == 0) {
#pragma unroll
    for (int e = 0; e < E_NUM; ++e) red[wv][e] = acc[e];
  }
  __syncthreads();
  if (tid == 0) {
#pragma unroll
    for (int e = 0; e < E_NUM; ++e)
      acc[e] = red[0][e] + red[1][e] + red[2][e] + red[3][e];
    int b0 = 0;
#pragma unroll
    for (int e = 1; e < E_NUM; ++e)
      if (acc[e] > acc[b0]) b0 = e;
    int b1 = (b0 == 0) ? 1 : 0;
#pragma unroll
    for (int e = 0; e < E_NUM; ++e)
      if (e != b0 && acc[e] > acc[b1] && e != b1) {
        if (e < b1 && acc[e] == acc[b1]) continue;
        if (acc[e] > acc[b1]) b1 = e;
      }
    double p0 = 1.0 / (1.0 + exp(acc[b1] - acc[b0]));
    sel[t * 2 + 0] = b0;
    sel[t * 2 + 1] = b1;
    wts[t * 2 + 0] = (float)p0;
    wts[t * 2 + 1] = (float)(1.0 - p0);
  }
}

// ---------------- K2: deterministic routing scan (single block, no atomics) ----------------
// Thread tid owns pairs [tid*32, tid*32+32). Stable order: position of pair p in
// expert e's group = offsets[e] + (#pairs<p with expert e).
__global__ __launch_bounds__(256) void route_scan_kernel(
    const int* __restrict__ sel, int* __restrict__ pos_of, int* __restrict__ offsets) {
  __shared__ int cnt[256 * E_NUM];   // 8 KB
  __shared__ int tot[E_NUM];
  const int tid = threadIdx.x;

  int4 sv[8];
  const int4* sp = (const int4*)(sel + tid * 32);
#pragma unroll
  for (int j = 0; j < 8; ++j) sv[j] = sp[j];

  int local[E_NUM];
#pragma unroll
  for (int e = 0; e < E_NUM; ++e) local[e] = 0;
#pragma unroll
  for (int j = 0; j < 8; ++j) {
#pragma unroll
    for (int e = 0; e < E_NUM; ++e)
      local[e] += (sv[j].x == e) + (sv[j].y == e) + (sv[j].z == e) + (sv[j].w == e);
  }
#pragma unroll
  for (int e = 0; e < E_NUM; ++e) cnt[tid * E_NUM + e] = local[e];
  __syncthreads();

  // 8 threads serially scan their expert's 256 counts (exclusive)
  if (tid < E_NUM) {
    int s = 0;
    for (int t = 0; t < 256; ++t) {
      int c = cnt[t * E_NUM + tid];
      cnt[t * E_NUM + tid] = s;
      s += c;
    }
    tot[tid] = s;
  }
  __syncthreads();
  if (tid == 0) {
    int s = 0;
    for (int e = 0; e < E_NUM; ++e) {
      int c = tot[e];
      tot[e] = s;
      offsets[e] = s;
      s += c;
    }
    offsets[E_NUM] = s;
  }
  __syncthreads();

  // fold expert base into this thread's running counters (own slots only)
#pragma unroll
  for (int e = 0; e < E_NUM; ++e) cnt[tid * E_NUM + e] += tot[e];

  // assign positions in pair order (LDS RMW on own slots keeps ordering)
#pragma unroll
  for (int j = 0; j < 8; ++j) {
    int p = tid * 32 + j * 4;
    int4 v = sv[j];
    int pos;
    pos = cnt[tid * E_NUM + v.x]++; pos_of[p + 0] = pos;
    pos = cnt[tid * E_NUM + v.y]++; pos_of[p + 1] = pos;
    pos = cnt[tid * E_NUM + v.z]++; pos_of[p + 2] = pos;
    pos = cnt[tid * E_NUM + v.w]++; pos_of[p + 3] = pos;
  }
}

// ---------------- K3: gather x row -> both compacted bf16 copies (no atomics) ----------------
__global__ __launch_bounds__(256) void gather_x_kernel(
    const float* __restrict__ x, const int* __restrict__ pos_of,
    uint16_t* __restrict__ xg) {
  int t = blockIdx.x;
  int d = threadIdx.x * 4;
  float4 v = *(const float4*)&x[(size_t)t * D_DIM + d];
  uint2 o;
  o.x = pack2(v.x, v.y);
  o.y = pack2(v.z, v.w);
  int i0 = pos_of[2 * t], i1 = pos_of[2 * t + 1];
  *(uint2*)&xg[(size_t)i0 * D_DIM + d] = o;
  *(uint2*)&xg[(size_t)i1 * D_DIM + d] = o;
}

// ---------------- K4: w1 cvt + g/v row de-interleave (proven R5) ----------------
__global__ __launch_bounds__(256) void cvt_w1_kernel(
    const float* __restrict__ w1, uint16_t* __restrict__ w1b) {
  int row = blockIdx.x;            // e*4096 + c_out
  int c_out = row & (C2F - 1);
  int e = row >> 12;
  int q = c_out >> 5, s = c_out & 31;
  int c_in = (q << 5) + ((s < 16) ? (s << 1) : (((s - 16) << 1) | 1));
  const float* src = w1 + ((size_t)e * C2F + c_in) * D_DIM + threadIdx.x * 4;
  float4 v = *(const float4*)src;
  uint2 o;
  o.x = pack2(v.x, v.y);
  o.y = pack2(v.z, v.w);
  *(uint2*)&w1b[(size_t)row * D_DIM + threadIdx.x * 4] = o;
}

// ---------------- K5: plain f32 -> bf16 convert (w2) ----------------
__global__ __launch_bounds__(256) void cvt_bf16_kernel(
    const float* __restrict__ src, uint16_t* __restrict__ dst, int n4) {
  int i = blockIdx.x * 256 + threadIdx.x;
  if (i >= n4) return;
  float4 v = ((const float4*)src)[i];
  uint2 o;
  o.x = pack2(v.x, v.y);
  o.y = pack2(v.z, v.w);
  ((uint2*)dst)[i] = o;
}

// LDS tile: 128 rows x 64 bf16 (BK=64); row = 128B = 8 chunks of 16B.
// Swizzle: slot s of row r holds k-chunk s ^ (r&7) — conflict-free (R5/R6-verified).

// ---------------- K6: GEMM1  f_act = swiglu(xg @ w1b^T + b1) ----------------
__global__ __launch_bounds__(256) void gemm1_kernel(
    const uint16_t* __restrict__ xg, const uint16_t* __restrict__ w1b,
    const float* __restrict__ b1, const int* __restrict__ offsets,
    uint16_t* __restrict__ f_act) {
  const int e = blockIdx.z;
  const int base = offsets[e];
  const int n_e = offsets[e + 1] - base;
  const int row0 = blockIdx.y * 128;
  if (row0 >= n_e) return;
  const int c0 = blockIdx.x * 128;

  __shared__ uint16_t As[128 * 64];   // 16 KB
  __shared__ uint16_t Bs[128 * 64];   // 16 KB

  const int tid = threadIdx.x;
  const int lane = tid & 63;
  const int wv = tid >> 6;
  const int wm = wv & 1, wn = wv >> 1;

  const int srow = lane >> 3;
  const int schunk = ((lane & 7) ^ srow) * 8;
  const uint16_t* agp[4]; uint16_t* alds[4];
  const uint16_t* bgp[4]; uint16_t* blds[4];
#pragma unroll
  for (int j = 0; j < 4; ++j) {
    int tr = wv * 32 + 8 * j + srow;
    int ag = base + row0 + tr; if (ag > NPAIR - 1) ag = NPAIR - 1;
    agp[j] = xg + (size_t)ag * D_DIM + schunk;
    alds[j] = &As[(wv * 32 + 8 * j) * 64];
    bgp[j] = w1b + ((size_t)e * C2F + c0 + tr) * D_DIM + schunk;
    blds[j] = &Bs[(wv * 32 + 8 * j) * 64];
  }

  f32x4 acc[4][4];
#pragma unroll
  for (int mi = 0; mi < 4; ++mi)
#pragma unroll
    for (int ni = 0; ni < 4; ++ni) acc[mi][ni] = (f32x4){0.f, 0.f, 0.f, 0.f};

  const int r15 = lane & 15;
  const int s0 = (lane >> 4) ^ (lane & 7);
  const uint16_t* Ard0 = &As[(wm * 64 + r15) * 64 + s0 * 8];
  const uint16_t* Ard1 = &As[(wm * 64 + r15) * 64 + (s0 ^ 4) * 8];
  const uint16_t* Brd0 = &Bs[(wn * 64 + r15) * 64 + s0 * 8];
  const uint16_t* Brd1 = &Bs[(wn * 64 + r15) * 64 + (s0 ^ 4) * 8];

#pragma unroll
  for (int kt = 0; kt < D_DIM / 64; ++kt) {
    __syncthreads();
#pragma unroll
    for (int j = 0; j < 4; ++j) gld_lds16(agp[j] + kt * 64, alds[j]);
#pragma unroll
    for (int j = 0; j < 4; ++j) gld_lds16(bgp[j] + kt * 64, blds[j]);
    __syncthreads();

#pragma unroll
    for (int h = 0; h < 2; ++h) {
      const uint16_t* Ard = h ? Ard1 : Ard0;
      const uint16_t* Brd = h ? Brd1 : Brd0;
      bf16x8 af[4], bfv[4];
#pragma unroll
      for (int mi = 0; mi < 4; ++mi) af[mi] = *(const bf16x8*)(Ard + mi * 16 * 64);
#pragma unroll
      for (int ni = 0; ni < 4; ++ni) bfv[ni] = *(const bf16x8*)(Brd + ni * 16 * 64);
#pragma unroll
      for (int mi = 0; mi < 4; ++mi)
#pragma unroll
        for (int ni = 0; ni < 4; ++ni)
          acc[mi][ni] = __builtin_amdgcn_mfma_f32_16x16x32_bf16(af[mi], bfv[ni], acc[mi][ni], 0, 0, 0);
    }
  }

  // epilogue: g/v in same lane (ni even=g, ni odd=v); 32 swiglu, no shfl (proven R5)
  const float* b1e = b1 + (size_t)e * C2F;
  const int rq = (lane >> 4) * 4;
#pragma unroll
  for (int ji = 0; ji < 2; ++ji) {
    int gbase = c0 + wn * 64 + ji * 32;
    float bg = b1e[gbase + 2 * r15];
    float bv = b1e[gbase + 2 * r15 + 1];
    int fcol = (gbase >> 1) + r15;
#pragma unroll
    for (int mi = 0; mi < 4; ++mi)
#pragma unroll
      for (int r = 0; r < 4; ++r) {
        float g = acc[mi][2 * ji][r] + bg;
        float v = acc[mi][2 * ji + 1][r] + bv;
        float f = swiglu_f(g, v);
        int row_l = wm * 64 + mi * 16 + rq + r;
        if (row0 + row_l < n_e)
          f_act[(size_t)(base + row0 + row_l) * F_DIM + fcol] = bf16h(f);
      }
  }
}

// ---------------- K7: GEMM2  y = f_act @ w2b^T + b2  (plain stores) ----------------
__global__ __launch_bounds__(256) void gemm2_kernel(
    const uint16_t* __restrict__ f_act, const uint16_t* __restrict__ w2b,
    const float* __restrict__ b2, const int* __restrict__ offsets,
    float* __restrict__ y) {
  const int e = blockIdx.z;
  const int base = offsets[e];
  const int n_e = offsets[e + 1] - base;
  const int row0 = blockIdx.y * 128;
  if (row0 >= n_e) return;
  const int c0 = blockIdx.x * 128;

  __shared__ uint16_t As[128 * 64];
  __shared__ uint16_t Bs[128 * 64];

  const int tid = threadIdx.x;
  const int lane = tid & 63;
  const int wv = tid >> 6;
  const int wm = wv & 1, wn = wv >> 1;

  const int srow = lane >> 3;
  const int schunk = ((lane & 7) ^ srow) * 8;
  const uint16_t* agp[4]; uint16_t* alds[4];
  const uint16_t* bgp[4]; uint16_t* blds[4];
#pragma unroll
  for (int j = 0; j < 4; ++j) {
    int tr = wv * 32 + 8 * j + srow;
    int ag = base + row0 + tr; if (ag > NPAIR - 1) ag = NPAIR - 1;
    agp[j] = f_act + (size_t)ag * F_DIM + schunk;
    alds[j] = &As[(wv * 32 + 8 * j) * 64];
    bgp[j] = w2b + ((size_t)e * D_DIM + c0 + tr) * F_DIM + schunk;
    blds[j] = &Bs[(wv * 32 + 8 * j) * 64];
  }

  f32x4 acc[4][4];
#pragma unroll
  for (int mi = 0; mi < 4; ++mi)
#pragma unroll
    for (int ni = 0; ni < 4; ++ni) acc[mi][ni] = (f32x4){0.f, 0.f, 0.f, 0.f};

  const int r15 = lane & 15;
  const int s0 = (lane >> 4) ^ (lane & 7);
  const uint16_t* Ard0 = &As[(wm * 64 + r15) * 64 + s0 * 8];
  const uint16_t* Ard1 = &As[(wm * 64 + r15) * 64 + (s0 ^ 4) * 8];
  const uint16_t* Brd0 = &Bs[(wn * 64 + r15) * 64 + s0 * 8];
  const uint16_t* Brd1 = &Bs[(wn * 64 + r15) * 64 + (s0 ^ 4) * 8];

#pragma unroll
  for (int kt = 0; kt < F_DIM / 64; ++kt) {
    __syncthreads();
#pragma unroll
    for (int j = 0; j < 4; ++j) gld_lds16(agp[j] + kt * 64, alds[j]);
#pragma unroll
    for (int j = 0; j < 4; ++j) gld_lds16(bgp[j] + kt * 64, blds[j]);
    __syncthreads();

#pragma unroll
    for (int h = 0; h < 2; ++h) {
      const uint16_t* Ard = h ? Ard1 : Ard0;
      const uint16_t* Brd = h ? Brd1 : Brd0;
      bf16x8 af[4], bfv[4];
#pragma unroll
      for (int mi = 0; mi < 4; ++mi) af[mi] = *(const bf16x8*)(Ard + mi * 16 * 64);
#pragma unroll
      for (int ni = 0; ni < 4; ++ni) bfv[ni] = *(const bf16x8*)(Brd + ni * 16 * 64);
#pragma unroll
      for (int mi = 0; mi < 4; ++mi)
#pragma unroll
        for (int ni = 0; ni < 4; ++ni)
          acc[mi][ni] = __builtin_amdgcn_mfma_f32_16x16x32_bf16(af[mi], bfv[ni], acc[mi][ni], 0, 0, 0);
    }
  }

  // epilogue: bias + plain stores into compacted y (no atomics; R4-measured-better)
  float bias4[4]; int d4a[4];
#pragma unroll
  for (int ni = 0; ni < 4; ++ni) {
    d4a[ni] = c0 + wn * 64 + ni * 16 + r15;
    bias4[ni] = b2[(size_t)e * D_DIM + d4a[ni]];
  }
  const int rq = (lane >> 4) * 4;
#pragma unroll
  for (int mi = 0; mi < 4; ++mi)
#pragma unroll
    for (int r = 0; r < 4; ++r) {
      int grow = row0 + wm * 64 + mi * 16 + rq + r;
      if (grow >= n_e) continue;
      size_t yb = (size_t)(base + grow) * D_DIM;
#pragma unroll
      for (int ni = 0; ni < 4; ++ni)
        y[yb + d4a[ni]] = acc[mi][ni][r] + bias4[ni];
    }
}

// ---------------- K8: combine the two expert outputs per token ----------------
__global__ __launch_bounds__(256) void combine_kernel(
    const float* __restrict__ y, const int* __restrict__ pos_of,
    const float* __restrict__ wts, float* __restrict__ out) {
  int t = blockIdx.x;
  int d4 = threadIdx.x * 4;
  int p0 = pos_of[t * 2], p1 = pos_of[t * 2 + 1];
  float w0 = wts[t * 2], w1v = wts[t * 2 + 1];
  float4 a = *(const float4*)&y[(size_t)p0 * D_DIM + d4];
  float4 b = *(const float4*)&y[(size_t)p1 * D_DIM + d4];
  float4 o;
  o.x = w0 * a.x + w1v * b.x;
  o.y = w0 * a.y + w1v * b.y;
  o.z = w0 * a.z + w1v * b.z;
  o.w = w0 * a.w + w1v * b.w;
  *(float4*)&out[(size_t)t * D_DIM + d4] = o;
}

extern "C" void kernel_launch(void* const* d_in, const int* in_sizes, int n_in,
                              void* d_out, int out_size, void* d_ws, size_t ws_size,
                              hipStream_t stream) {
  const float* x      = (const float*)d_in[0];
  const float* gate_w = (const float*)d_in[1];
  const float* w1     = (const float*)d_in[2];
  const float* b1     = (const float*)d_in[3];
  const float* w2     = (const float*)d_in[4];
  const float* b2     = (const float*)d_in[5];
  float* out = (float*)d_out;

  char* ws = (char*)d_ws;
  int*      offsets = (int*)(ws + OFF_OFFSETS);
  int*      sel     = (int*)(ws + OFF_SEL);
  float*    wts     = (float*)(ws + OFF_WTS);
  int*      pos_of  = (int*)(ws + OFF_POSOF);
  uint16_t* f_act   = (uint16_t*)(ws + OFF_FACT);
  uint16_t* xg      = (uint16_t*)(ws + OFF_XG);
  uint16_t* w1b     = (uint16_t*)(ws + OFF_WB);
  uint16_t* w2b     = (uint16_t*)(ws + OFF_WB);   // reuses w1b region after gemm1
  float*    yb      = (float*)(ws + OFF_Y);       // overlays w1b tail

  cvt_w1_kernel<<<E_NUM * C2F, 256, 0, stream>>>(w1, w1b);
  gate_route_kernel<<<T_TOK, 256, 0, stream>>>(x, gate_w, sel, wts);
  route_scan_kernel<<<1, 256, 0, stream>>>(sel, pos_of, offsets);
  gather_x_kernel<<<T_TOK, 256, 0, stream>>>(x, pos_of, xg);
  gemm1_kernel<<<dim3(C2F / 128, 64, E_NUM), 256, 0, stream>>>(xg, w1b, b1, offsets, f_act);
  cvt_bf16_kernel<<<(E_NUM * D_DIM * F_DIM / 4) / 256, 256, 0, stream>>>(
      w2, w2b, E_NUM * D_DIM * F_DIM / 4);
  gemm2_kernel<<<dim3(D_DIM / 128, 64, E_NUM), 256, 0, stream>>>(f_act, w2b, b2, offsets, yb);
  combine_kernel<<<T_TOK, 256, 0, stream>>>(yb, pos_of, wts, out);
}